// Round 4
// baseline (1953.198 us; speedup 1.0000x reference)
//
#include <hip/hip_runtime.h>
#include <hip/hip_bf16.h>
#include <stdint.h>

// ---------------------------------------------------------------------------
// Attention_53712861003822 : B=4 S=1024 D=4096, HQ=32 HKV=8 HD=128, GQA 4:1
// Round 8:
//  (a) gemm_bt fast path (A,B both bf16): global_load_lds width=16 staging
//      into linear [128][64] LDS (m97 structure, proven 874 TF). Slow path
//      (any fp32 operand) = round-3 code, unchanged.
//  (b) Wk/Wv converted to bf16 in d_out[48,64M) (fp32 mode) so K/V GEMMs
//      take the fast path as well.
//  (c) attn: bijective XCD swizzle (each XCD owns 4 complete (b,kh) panel
//      groups -> K/V L2-resident, fetched once), Q fragments hoisted to
//      registers, phase-3 unroll 4 under __launch_bounds__(256,4).
// Memory plan (fp32 mode): ws[0,32M)=Qb (+ optional Wq_b/Wo_b at 32/64M);
// d_out[0,8M)=Kb, [8,16M)=Vt, [16,48M)=hs_b, [48,56M)=Wk_b, [56,64M)=Wv_b
// (all dead before the final GEMM overwrites d_out).
// ---------------------------------------------------------------------------

typedef __attribute__((ext_vector_type(8))) short s8_t;     // 8 x bf16
typedef __attribute__((ext_vector_type(4))) float f4_t;     // MFMA acc
typedef __attribute__((ext_vector_type(4))) unsigned short us4_t;

#define MFMA16(a, b, c) __builtin_amdgcn_mfma_f32_16x16x32_bf16((a), (b), (c), 0, 0, 0)

__device__ __forceinline__ float b2f(unsigned short u) {
  union { unsigned int i; float f; } x; x.i = ((unsigned int)u) << 16; return x.f;
}
__device__ __forceinline__ unsigned short f2b(float f) {
  union { float f; unsigned int i; } x; x.f = f;
  unsigned int r = x.i + 0x7fff + ((x.i >> 16) & 1);   // RNE
  return (unsigned short)(r >> 16);
}

// Async global->LDS, 16B per lane. LDS dest must be wave-uniform base +
// lane*16 (our staging layout is exactly lane-linear). Integer casts avoid
// addrspacecast restrictions: generic LDS ptr low 32 bits == LDS offset.
__device__ __forceinline__ void gload16(const unsigned short* g, unsigned short* l) {
  __builtin_amdgcn_global_load_lds(
      (const __attribute__((address_space(1))) void*)(uintptr_t)g,
      (__attribute__((address_space(3))) void*)(unsigned int)(uintptr_t)l,
      16, 0, 0);
}

// Probe 64 ushorts at `off` as bf16; large-exponent/NaN patterns => fp32 data.
__device__ __forceinline__ bool probe_is_f32_off(const void* p, int off) {
  if (!p) return false;
  const unsigned short* u = (const unsigned short*)p + off;
  bool f = false;
#pragma unroll
  for (int i = 0; i < 64; ++i) {
    const float v = b2f(u[i]);
    f |= !(fabsf(v) < 1e8f);      // catches huge exponents AND NaN
  }
  return f;
}
__device__ __forceinline__ bool probe_is_f32(const void* p) {
  return probe_is_f32_off(p, 0);
}

__device__ __forceinline__ s8_t cvt8(const float* p) {
  const float4 a = *(const float4*)(p);
  const float4 b = *(const float4*)(p + 4);
  union { s8_t v; __hip_bfloat162 h[4]; } t;
  t.h[0] = __float22bfloat162_rn(make_float2(a.x, a.y));
  t.h[1] = __float22bfloat162_rn(make_float2(a.z, a.w));
  t.h[2] = __float22bfloat162_rn(make_float2(b.x, b.y));
  t.h[3] = __float22bfloat162_rn(make_float2(b.z, b.w));
  return t.v;
}

// 8 consecutive elements starting at elem offset `off` (8-aligned) as bf16x8.
__device__ __forceinline__ s8_t load8(const void* base, size_t off, bool f32) {
  if (f32) return cvt8((const float*)base + off);
  return *(const s8_t*)((const unsigned short*)base + off);
}

// ---------------------------------------------------------------------------
// One-shot fp32->bf16 (or bf16 copy) conversion, 8 elems/thread.
// ---------------------------------------------------------------------------
__global__ __launch_bounds__(256) void cvt_to_bf16(
    unsigned short* __restrict__ out, const void* __restrict__ in)
{
  const bool f = probe_is_f32(in);
  const size_t i = ((size_t)blockIdx.x * 256 + threadIdx.x) * 8;
  if (f) *(s8_t*)(out + i) = cvt8((const float*)in + i);
  else   *(s8_t*)(out + i) = *(const s8_t*)((const unsigned short*)in + i);
}

// ---------------------------------------------------------------------------
// C[M,N] = A[M,K] @ B[N,K]^T  (row-major, fp32 acc). A/B fp32-or-bf16 per
// probe; C bf16 (probeC=null) or fp32. transC: write C^T (bf16 only), packed
// 4-row us4 stores -> Ct[n][m] layout. 128x128 tile, BK=64, 4 waves.
// Fast path (both operands bf16): global_load_lds staging, linear LDS LP=64.
// Slow path: reg-staged with in-flight fp32->bf16 cvt, LDS LP=72.
// ---------------------------------------------------------------------------
__global__ __launch_bounds__(256) void gemm_bt(
    void* __restrict__ C,
    const void* __restrict__ A,
    const void* __restrict__ B,
    int M, int N, int K,
    const void* probeA, const void* probeB, const void* probeC,
    int transC)
{
  constexpr int LP = 72;
  __shared__ unsigned short sA[128 * LP];
  __shared__ unsigned short sB[128 * LP];
  const bool fA = probe_is_f32(probeA);
  const bool fB = probe_is_f32(probeB);
  const bool fC = probe_is_f32(probeC);

  const int tid  = threadIdx.x;
  const int lane = tid & 63;
  const int wv   = tid >> 6;
  const int wr   = (wv >> 1) * 64;
  const int wc   = (wv & 1) * 64;
  const int quad = lane >> 4;
  const int l16  = lane & 15;
  const int m0 = blockIdx.x * 128;
  const int n0 = blockIdx.y * 128;

  f4_t acc[4][4];
#pragma unroll
  for (int i = 0; i < 4; ++i)
#pragma unroll
    for (int j = 0; j < 4; ++j) acc[i][j] = (f4_t){0.f, 0.f, 0.f, 0.f};

  int srow[4], scol[4];
#pragma unroll
  for (int it = 0; it < 4; ++it) {
    const int s = it * 256 + tid;
    srow[it] = s >> 3;
    scol[it] = (s & 7) * 8;
  }

  const int nK = K >> 6;

  if (!fA && !fB) {
    // ---- fast path: both bf16, async global->LDS staging, linear LP=64 ----
    const unsigned short* Ag = (const unsigned short*)A;
    const unsigned short* Bg = (const unsigned short*)B;
    for (int kt = 0; kt < nK; ++kt) {
      const int k0 = kt << 6;
#pragma unroll
      for (int it = 0; it < 4; ++it) {
        const int s = it * 256 + tid;
        gload16(Ag + (size_t)(m0 + srow[it]) * K + k0 + scol[it], &sA[s * 8]);
        gload16(Bg + (size_t)(n0 + srow[it]) * K + k0 + scol[it], &sB[s * 8]);
      }
      __syncthreads();
#pragma unroll
      for (int kc = 0; kc < 2; ++kc) {
        s8_t af[4], bfr[4];
#pragma unroll
        for (int i = 0; i < 4; ++i) {
          af[i]  = *(const s8_t*)(&sA[(wr + i * 16 + l16) * 64 + (kc * 4 + quad) * 8]);
          bfr[i] = *(const s8_t*)(&sB[(wc + i * 16 + l16) * 64 + (kc * 4 + quad) * 8]);
        }
#pragma unroll
        for (int i = 0; i < 4; ++i)
#pragma unroll
          for (int j = 0; j < 4; ++j)
            acc[i][j] = MFMA16(af[i], bfr[j], acc[i][j]);
      }
      __syncthreads();
    }
  } else {
    // ---- slow path: reg-staged, adaptive dtype, LP=72 ----
    for (int kt = 0; kt < nK; ++kt) {
      const int k0 = kt << 6;
      s8_t va[4], vb[4];
#pragma unroll
      for (int it = 0; it < 4; ++it) {
        va[it] = load8(A, (size_t)(m0 + srow[it]) * K + k0 + scol[it], fA);
        vb[it] = load8(B, (size_t)(n0 + srow[it]) * K + k0 + scol[it], fB);
      }
#pragma unroll
      for (int it = 0; it < 4; ++it) {
        *(s8_t*)(&sA[srow[it] * LP + scol[it]]) = va[it];
        *(s8_t*)(&sB[srow[it] * LP + scol[it]]) = vb[it];
      }
      __syncthreads();
#pragma unroll
      for (int kc = 0; kc < 2; ++kc) {
        s8_t af[4], bfr[4];
#pragma unroll
        for (int i = 0; i < 4; ++i) {
          af[i]  = *(const s8_t*)(&sA[(wr + i * 16 + l16) * LP + (kc * 4 + quad) * 8]);
          bfr[i] = *(const s8_t*)(&sB[(wc + i * 16 + l16) * LP + (kc * 4 + quad) * 8]);
        }
#pragma unroll
        for (int i = 0; i < 4; ++i)
#pragma unroll
          for (int j = 0; j < 4; ++j)
            acc[i][j] = MFMA16(af[i], bfr[j], acc[i][j]);
      }
      __syncthreads();
    }
  }

  // epilogue: C/D layout col = lane&15, row = quad*4 + reg
  if (transC) {
#pragma unroll
    for (int i = 0; i < 4; ++i) {
      const int rbase = m0 + wr + i * 16 + quad * 4;
#pragma unroll
      for (int j = 0; j < 4; ++j) {
        const int col = n0 + wc + j * 16 + l16;
        us4_t t;
#pragma unroll
        for (int rg = 0; rg < 4; ++rg) t[rg] = f2b(acc[i][j][rg]);
        *(us4_t*)(&((unsigned short*)C)[(size_t)col * M + rbase]) = t;
      }
    }
  } else {
#pragma unroll
    for (int i = 0; i < 4; ++i) {
      const int rbase = m0 + wr + i * 16 + quad * 4;
#pragma unroll
      for (int j = 0; j < 4; ++j) {
        const int col = n0 + wc + j * 16 + l16;
#pragma unroll
        for (int rg = 0; rg < 4; ++rg) {
          const size_t idx = (size_t)(rbase + rg) * N + col;
          if (fC) ((float*)C)[idx] = acc[i][j][rg];
          else    ((unsigned short*)C)[idx] = f2b(acc[i][j][rg]);
        }
      }
    }
  }
}

// ---------------------------------------------------------------------------
// RoPE in-place on bf16 X = (B,S,nh,128), vectorized 8 elems/thread.
// out[j] = x[j]*cos[s,64+j] - x[64+j]*sin[s,64+j]; out[64+j] = x2*c + x1*s.
// mode: 0 = device probe (offset 2048, cos|sin), 1 = force fp32, 2 = bf16.
// ---------------------------------------------------------------------------
__global__ __launch_bounds__(256) void rope_kernel(
    unsigned short* __restrict__ X,
    const void* __restrict__ cosb,
    const void* __restrict__ sinb,
    int log2nh, int mode)
{
  bool f;
  if (mode == 1)      f = true;
  else if (mode == 2) f = false;
  else f = probe_is_f32_off(cosb, 2048) | probe_is_f32_off(sinb, 2048);
  const size_t idx = (size_t)blockIdx.x * 256 + threadIdx.x;
  const int jb = (int)(idx & 7) * 8;
  const size_t row = idx >> 3;                 // (b*S+s)*nh + h
  const int s = (int)((row >> log2nh) & 1023);
  unsigned short* p = X + row * 128;
  union { s8_t v; unsigned short u[8]; } ua, ub, o1, o2;
  ua.v = *(const s8_t*)(p + jb);
  ub.v = *(const s8_t*)(p + 64 + jb);
#pragma unroll
  for (int j = 0; j < 8; ++j) {
    const int ci = s * 128 + 64 + jb + j;
    const float c  = f ? ((const float*)cosb)[ci] : b2f(((const unsigned short*)cosb)[ci]);
    const float sn = f ? ((const float*)sinb)[ci] : b2f(((const unsigned short*)sinb)[ci]);
    const float x1 = b2f(ua.u[j]);
    const float x2 = b2f(ub.u[j]);
    o1.u[j] = f2b(x1 * c - x2 * sn);
    o2.u[j] = f2b(x2 * c + x1 * sn);
  }
  *(s8_t*)(p + jb)      = o1.v;
  *(s8_t*)(p + 64 + jb) = o2.v;
}

// ---------------------------------------------------------------------------
// Attention: one block per (b, h, 16 q-rows), S=1024. O aliases Q (in-place).
// XCD-swizzled bid: hardware wg w runs logical block (w&7)*1024 + (w>>3),
// so XCD x owns logical range [x*1024,(x+1)*1024) = 4 complete (b,kh) panel
// groups -> K/V (2MB) L2-resident per XCD, fetched once.
// K direct from global; V direct from global in TRANSPOSED layout
// Vt[kh*128+d][b*1024+s]. Q fragments hoisted to registers for phase 1.
// ---------------------------------------------------------------------------
__global__ __launch_bounds__(256, 4) void attn_kernel(
    unsigned short* O,
    const unsigned short* Q,
    const unsigned short* __restrict__ Kb,
    const unsigned short* __restrict__ Vt)
{
  constexpr int S = 1024, HQ = 32, HKV = 8, HD = 128;
  constexpr int SCP = 1048;
  constexpr int QP  = 152;
  constexpr float SCALE = 0.08838834764831845f;  // 1/sqrt(128)
  __shared__ unsigned short sc[16 * SCP];
  __shared__ unsigned short sq[16 * QP];
  __shared__ float s_linv[16];

  const int bid = (((int)blockIdx.x & 7) << 10) | ((int)blockIdx.x >> 3);
  const int qt = bid & 63;
  const int h  = (bid >> 6) & 31;
  const int b  = bid >> 11;
  const int kh = h >> 2;
  const int tid  = threadIdx.x;
  const int lane = tid & 63;
  const int wv   = tid >> 6;
  const int quad = lane >> 4;
  const int l16  = lane & 15;

  const unsigned short* Qg = Q  + ((size_t)(b * S + qt * 16) * HQ + h) * HD;
  const unsigned short* Kg = Kb + ((size_t)b * S * HKV + kh) * HD;
  const unsigned short* Vg = Vt + ((size_t)kh * HD) * 4096 + (size_t)b * S;

  {
    const int r = tid >> 4, c = (tid & 15) * 8;
    *(s8_t*)(&sq[r * QP + c]) = *(const s8_t*)(Qg + (size_t)r * (HQ * HD) + c);
  }
  __syncthreads();

  // ---- phase 1: scores (K direct from global, Q hoisted to regs) ----
  s8_t qa[4];
#pragma unroll
  for (int kc = 0; kc < 4; ++kc)
    qa[kc] = *(const s8_t*)(&sq[l16 * QP + kc * 32 + quad * 8]);
#pragma unroll 2
  for (int kt = 0; kt < 16; ++kt) {
    const int ks = wv * 256 + kt * 16;
    f4_t acc = (f4_t){0.f, 0.f, 0.f, 0.f};
#pragma unroll
    for (int kc = 0; kc < 4; ++kc) {
      const s8_t kf = *(const s8_t*)(Kg + (size_t)(ks + l16) * (HKV * HD) + kc * 32 + quad * 8);
      acc = MFMA16(qa[kc], kf, acc);
    }
#pragma unroll
    for (int rg = 0; rg < 4; ++rg)
      sc[(quad * 4 + rg) * SCP + ks + l16] = f2b(acc[rg] * SCALE);
  }
  __syncthreads();

  // ---- phase 2: softmax (vectorized b128 row passes) ----
  {
    const int r = tid >> 4, c0 = tid & 15;
    unsigned short* srow = &sc[r * SCP + c0 * 8];
    float mx = -1e30f;
#pragma unroll
    for (int u = 0; u < 8; ++u) {
      union { s8_t v; unsigned short us[8]; } t;
      t.v = *(const s8_t*)(srow + u * 128);
#pragma unroll
      for (int j = 0; j < 8; ++j) mx = fmaxf(mx, b2f(t.us[j]));
    }
#pragma unroll
    for (int off = 8; off; off >>= 1) mx = fmaxf(mx, __shfl_xor(mx, off, 16));
    float sum = 0.f;
#pragma unroll
    for (int u = 0; u < 8; ++u) {
      union { s8_t v; unsigned short us[8]; } t;
      t.v = *(const s8_t*)(srow + u * 128);
#pragma unroll
      for (int j = 0; j < 8; ++j) {
        const float e = __expf(b2f(t.us[j]) - mx);
        sum += e;
        t.us[j] = f2b(e);
      }
      *(s8_t*)(srow + u * 128) = t.v;
    }
#pragma unroll
    for (int off = 8; off; off >>= 1) sum += __shfl_xor(sum, off, 16);
    if (c0 == 0) s_linv[r] = 1.0f / sum;
  }
  __syncthreads();

  // ---- phase 3: O = P @ Vt (V direct from global, no barriers) ----
  f4_t oacc[2];
  oacc[0] = (f4_t){0.f, 0.f, 0.f, 0.f};
  oacc[1] = (f4_t){0.f, 0.f, 0.f, 0.f};
  const unsigned short* vb0 = Vg + (size_t)(wv * 32 + l16) * 4096 + quad * 8;
  const unsigned short* vb1 = vb0 + (size_t)16 * 4096;
  const unsigned short* prow = &sc[l16 * SCP + quad * 8];
#pragma unroll 4
  for (int ck = 0; ck < 16; ++ck) {
#pragma unroll
    for (int kc = 0; kc < 2; ++kc) {
      const int ko = ck * 64 + kc * 32;
      const s8_t pa = *(const s8_t*)(prow + ko);
      const s8_t v0 = *(const s8_t*)(vb0 + ko);
      const s8_t v1 = *(const s8_t*)(vb1 + ko);
      oacc[0] = MFMA16(pa, v0, oacc[0]);
      oacc[1] = MFMA16(pa, v1, oacc[1]);
    }
  }

#pragma unroll
  for (int dt = 0; dt < 2; ++dt)
#pragma unroll
    for (int rg = 0; rg < 4; ++rg) {
      const int r = quad * 4 + rg;
      const int d = wv * 32 + dt * 16 + l16;
      O[((size_t)(b * S + qt * 16 + r) * HQ + h) * HD + d] =
          f2b(oacc[dt][rg] * s_linv[r]);
    }
}

// ---------------------------------------------------------------------------
extern "C" void kernel_launch(void* const* d_in, const int* in_sizes, int n_in,
                              void* d_out, int out_size, void* d_ws, size_t ws_size,
                              hipStream_t stream)
{
  const void* hs   = d_in[0];
  const void* cosb = d_in[1];
  const void* sinb = d_in[2];
  const void* Wq   = d_in[3];
  const void* Wk   = d_in[4];
  const void* Wv   = d_in[5];
  const void* Wo   = d_in[6];

  const size_t MB = (size_t)1 << 20;
  // fp32 input mode <=> hs is (4,1024,4096) fp32 = 64MB (bf16 mode: 32MB).
  const bool f32in = (n_in >= 1 && in_sizes && in_sizes[0] == (int)(64 * MB));
  // cos/sin dtype for rope: decide host-side when sizes match; else probe.
  int rmode = 0;
  if (in_sizes && n_in >= 2) {
    if (in_sizes[1] == 524288) rmode = 1;        // (1,1024,128) fp32
    else if (in_sizes[1] == 262144) rmode = 2;   // (1,1024,128) bf16
  }

  unsigned short* Qb = (unsigned short*)d_ws;                    // ws[0,32M)
  unsigned short* Kb = (unsigned short*)d_out;                   // d_out[0,8M)
  unsigned short* Vt = (unsigned short*)d_out + 4194304;         // d_out[8,16M)

  // One-shot bf16 operand conversion (fp32 mode only; layout gated on sizes).
  const void* hsA = hs;
  if (f32in && out_size >= (int)(48 * MB)) {
    unsigned short* hs_b = (unsigned short*)d_out + 8388608;     // d_out[16,48M)
    cvt_to_bf16<<<8192, 256, 0, stream>>>(hs_b, hs);
    hsA = hs_b;
  }
  const void* WkB = Wk;
  const void* WvB = Wv;
  if (f32in && out_size >= (int)(64 * MB)) {
    unsigned short* wk_b = (unsigned short*)d_out + 25165824;    // d_out[48,56M)
    unsigned short* wv_b = (unsigned short*)d_out + 29360128;    // d_out[56,64M)
    cvt_to_bf16<<<2048, 256, 0, stream>>>(wk_b, Wk);
    cvt_to_bf16<<<2048, 256, 0, stream>>>(wv_b, Wv);
    WkB = wk_b;
    WvB = wv_b;
  }
  const void* WqB = Wq;
  if (f32in && ws_size >= 64 * MB) {
    unsigned short* wq_b = (unsigned short*)d_ws + 16777216;     // ws[32,64M)
    cvt_to_bf16<<<8192, 256, 0, stream>>>(wq_b, Wq);
    WqB = wq_b;
  }
  const void* WoB = Wo;
  if (f32in && ws_size >= 96 * MB) {
    unsigned short* wo_b = (unsigned short*)d_ws + 33554432;     // ws[64,96M)
    cvt_to_bf16<<<8192, 256, 0, stream>>>(wo_b, Wo);
    WoB = wo_b;
  }

  gemm_bt<<<dim3(32,  8), 256, 0, stream>>>(Kb, hsA, WkB, 4096, 1024, 4096,
                                            hsA, WkB, nullptr, 0);
  gemm_bt<<<dim3(32,  8), 256, 0, stream>>>(Vt, hsA, WvB, 4096, 1024, 4096,
                                            hsA, WvB, nullptr, 1);
  gemm_bt<<<dim3(32, 32), 256, 0, stream>>>(Qb, hsA, WqB, 4096, 4096, 4096,
                                            hsA, WqB, nullptr, 0);
  rope_kernel<<<4096, 256, 0, stream>>>(Qb, cosb, sinb, 5, rmode);
  rope_kernel<<<1024, 256, 0, stream>>>(Kb, cosb, sinb, 3, rmode);
  attn_kernel<<<4 * 32 * 64, 256, 0, stream>>>(Qb, Qb, Kb, Vt);
  // final projection: A=Qb (bf16), B=Wo(/bf16 copy), C=d_out (input dtype)
  gemm_bt<<<dim3(32, 32), 256, 0, stream>>>(d_out, Qb, WoB, 4096, 4096, 4096,
                                            nullptr, WoB, hs, 0);
}

// Round 5
// 1948.780 us; speedup vs baseline: 1.0023x; 1.0023x over previous
//
#include <hip/hip_runtime.h>
#include <hip/hip_bf16.h>
#include <stdint.h>

// ---------------------------------------------------------------------------
// Attention_53712861003822 : B=4 S=1024 D=4096, HQ=32 HKV=8 HD=128, GQA 4:1
// Round 9 = Round 8 + ONE fix: wave-uniform LDS base for global_load_lds.
//  Round-8 evidence: fast path ran (FETCH 327MB == all-bf16 model) yet Q/final
//  GEMMs stayed at 470us = 293 TF, and global_load_lds == reg-staged timing.
//  Theory: &sA[s*8] with s=it*256+tid is lane-DIVERGENT; global_load_lds
//  takes its LDS dest via M0 (wave-uniform) + lane*16 in hardware. Divergent
//  pointer => compiler waterfalls 64x (correct results, ~50x slower staging).
//  Fix: pass &sA[(it*256 + wvu*64)*8], wvu = readfirstlane(wave id); the HW
//  lane*16 scatter reproduces the identical LDS layout.
// Memory plan (fp32 mode): ws[0,32M)=Qb, ws[32,64M)=Wq_b, ws[64,96M)=Wo_b;
// d_out[0,8M)=Kb, [8,16M)=Vt, [16,48M)=hs_b, [48,56M)=Wk_b, [56,64M)=Wv_b
// (all dead before the final GEMM overwrites d_out).
// ---------------------------------------------------------------------------

typedef __attribute__((ext_vector_type(8))) short s8_t;     // 8 x bf16
typedef __attribute__((ext_vector_type(4))) float f4_t;     // MFMA acc
typedef __attribute__((ext_vector_type(4))) unsigned short us4_t;

#define MFMA16(a, b, c) __builtin_amdgcn_mfma_f32_16x16x32_bf16((a), (b), (c), 0, 0, 0)

__device__ __forceinline__ float b2f(unsigned short u) {
  union { unsigned int i; float f; } x; x.i = ((unsigned int)u) << 16; return x.f;
}
__device__ __forceinline__ unsigned short f2b(float f) {
  union { float f; unsigned int i; } x; x.f = f;
  unsigned int r = x.i + 0x7fff + ((x.i >> 16) & 1);   // RNE
  return (unsigned short)(r >> 16);
}

// Async global->LDS, 16B per lane. l MUST be wave-uniform: HW writes LDS at
// M0(base) + lane*16. Integer casts: generic LDS ptr low 32 bits == offset.
__device__ __forceinline__ void gload16(const unsigned short* g, unsigned short* l) {
  __builtin_amdgcn_global_load_lds(
      (const __attribute__((address_space(1))) void*)(uintptr_t)g,
      (__attribute__((address_space(3))) void*)(unsigned int)(uintptr_t)l,
      16, 0, 0);
}

// Probe 64 ushorts at `off` as bf16; large-exponent/NaN patterns => fp32 data.
__device__ __forceinline__ bool probe_is_f32_off(const void* p, int off) {
  if (!p) return false;
  const unsigned short* u = (const unsigned short*)p + off;
  bool f = false;
#pragma unroll
  for (int i = 0; i < 64; ++i) {
    const float v = b2f(u[i]);
    f |= !(fabsf(v) < 1e8f);      // catches huge exponents AND NaN
  }
  return f;
}
__device__ __forceinline__ bool probe_is_f32(const void* p) {
  return probe_is_f32_off(p, 0);
}

__device__ __forceinline__ s8_t cvt8(const float* p) {
  const float4 a = *(const float4*)(p);
  const float4 b = *(const float4*)(p + 4);
  union { s8_t v; __hip_bfloat162 h[4]; } t;
  t.h[0] = __float22bfloat162_rn(make_float2(a.x, a.y));
  t.h[1] = __float22bfloat162_rn(make_float2(a.z, a.w));
  t.h[2] = __float22bfloat162_rn(make_float2(b.x, b.y));
  t.h[3] = __float22bfloat162_rn(make_float2(b.z, b.w));
  return t.v;
}

// 8 consecutive elements starting at elem offset `off` (8-aligned) as bf16x8.
__device__ __forceinline__ s8_t load8(const void* base, size_t off, bool f32) {
  if (f32) return cvt8((const float*)base + off);
  return *(const s8_t*)((const unsigned short*)base + off);
}

// ---------------------------------------------------------------------------
// One-shot fp32->bf16 (or bf16 copy) conversion, 8 elems/thread.
// ---------------------------------------------------------------------------
__global__ __launch_bounds__(256) void cvt_to_bf16(
    unsigned short* __restrict__ out, const void* __restrict__ in)
{
  const bool f = probe_is_f32(in);
  const size_t i = ((size_t)blockIdx.x * 256 + threadIdx.x) * 8;
  if (f) *(s8_t*)(out + i) = cvt8((const float*)in + i);
  else   *(s8_t*)(out + i) = *(const s8_t*)((const unsigned short*)in + i);
}

// ---------------------------------------------------------------------------
// C[M,N] = A[M,K] @ B[N,K]^T  (row-major, fp32 acc). A/B fp32-or-bf16 per
// probe; C bf16 (probeC=null) or fp32. transC: write C^T (bf16 only), packed
// 4-row us4 stores -> Ct[n][m] layout. 128x128 tile, BK=64, 4 waves.
// Fast path (both operands bf16): global_load_lds staging (wave-uniform LDS
// base + HW lane*16 scatter), linear LDS LP=64. Slow path: reg-staged with
// in-flight fp32->bf16 cvt, LDS LP=72.
// ---------------------------------------------------------------------------
__global__ __launch_bounds__(256) void gemm_bt(
    void* __restrict__ C,
    const void* __restrict__ A,
    const void* __restrict__ B,
    int M, int N, int K,
    const void* probeA, const void* probeB, const void* probeC,
    int transC)
{
  constexpr int LP = 72;
  __shared__ unsigned short sA[128 * LP];
  __shared__ unsigned short sB[128 * LP];
  const bool fA = probe_is_f32(probeA);
  const bool fB = probe_is_f32(probeB);
  const bool fC = probe_is_f32(probeC);

  const int tid  = threadIdx.x;
  const int lane = tid & 63;
  const int wv   = tid >> 6;
  const int wr   = (wv >> 1) * 64;
  const int wc   = (wv & 1) * 64;
  const int quad = lane >> 4;
  const int l16  = lane & 15;
  const int m0 = blockIdx.x * 128;
  const int n0 = blockIdx.y * 128;

  f4_t acc[4][4];
#pragma unroll
  for (int i = 0; i < 4; ++i)
#pragma unroll
    for (int j = 0; j < 4; ++j) acc[i][j] = (f4_t){0.f, 0.f, 0.f, 0.f};

  int srow[4], scol[4];
#pragma unroll
  for (int it = 0; it < 4; ++it) {
    const int s = it * 256 + tid;
    srow[it] = s >> 3;
    scol[it] = (s & 7) * 8;
  }

  const int nK = K >> 6;

  if (!fA && !fB) {
    // ---- fast path: both bf16, async global->LDS staging, linear LP=64 ----
    // LDS dest base is wave-uniform (readfirstlane); HW scatters lane i to
    // base + i*16B, which equals &s?[ (it*256+tid)*8 ] for lane tid&63.
    const unsigned short* Ag = (const unsigned short*)A;
    const unsigned short* Bg = (const unsigned short*)B;
    const int wvu = __builtin_amdgcn_readfirstlane(wv);
    for (int kt = 0; kt < nK; ++kt) {
      const int k0 = kt << 6;
#pragma unroll
      for (int it = 0; it < 4; ++it) {
        const int su = (it * 256 + wvu * 64) * 8;   // wave-uniform LDS base
        gload16(Ag + (size_t)(m0 + srow[it]) * K + k0 + scol[it], &sA[su]);
        gload16(Bg + (size_t)(n0 + srow[it]) * K + k0 + scol[it], &sB[su]);
      }
      __syncthreads();
#pragma unroll
      for (int kc = 0; kc < 2; ++kc) {
        s8_t af[4], bfr[4];
#pragma unroll
        for (int i = 0; i < 4; ++i) {
          af[i]  = *(const s8_t*)(&sA[(wr + i * 16 + l16) * 64 + (kc * 4 + quad) * 8]);
          bfr[i] = *(const s8_t*)(&sB[(wc + i * 16 + l16) * 64 + (kc * 4 + quad) * 8]);
        }
#pragma unroll
        for (int i = 0; i < 4; ++i)
#pragma unroll
          for (int j = 0; j < 4; ++j)
            acc[i][j] = MFMA16(af[i], bfr[j], acc[i][j]);
      }
      __syncthreads();
    }
  } else {
    // ---- slow path: reg-staged, adaptive dtype, LP=72 ----
    for (int kt = 0; kt < nK; ++kt) {
      const int k0 = kt << 6;
      s8_t va[4], vb[4];
#pragma unroll
      for (int it = 0; it < 4; ++it) {
        va[it] = load8(A, (size_t)(m0 + srow[it]) * K + k0 + scol[it], fA);
        vb[it] = load8(B, (size_t)(n0 + srow[it]) * K + k0 + scol[it], fB);
      }
#pragma unroll
      for (int it = 0; it < 4; ++it) {
        *(s8_t*)(&sA[srow[it] * LP + scol[it]]) = va[it];
        *(s8_t*)(&sB[srow[it] * LP + scol[it]]) = vb[it];
      }
      __syncthreads();
#pragma unroll
      for (int kc = 0; kc < 2; ++kc) {
        s8_t af[4], bfr[4];
#pragma unroll
        for (int i = 0; i < 4; ++i) {
          af[i]  = *(const s8_t*)(&sA[(wr + i * 16 + l16) * LP + (kc * 4 + quad) * 8]);
          bfr[i] = *(const s8_t*)(&sB[(wc + i * 16 + l16) * LP + (kc * 4 + quad) * 8]);
        }
#pragma unroll
        for (int i = 0; i < 4; ++i)
#pragma unroll
          for (int j = 0; j < 4; ++j)
            acc[i][j] = MFMA16(af[i], bfr[j], acc[i][j]);
      }
      __syncthreads();
    }
  }

  // epilogue: C/D layout col = lane&15, row = quad*4 + reg
  if (transC) {
#pragma unroll
    for (int i = 0; i < 4; ++i) {
      const int rbase = m0 + wr + i * 16 + quad * 4;
#pragma unroll
      for (int j = 0; j < 4; ++j) {
        const int col = n0 + wc + j * 16 + l16;
        us4_t t;
#pragma unroll
        for (int rg = 0; rg < 4; ++rg) t[rg] = f2b(acc[i][j][rg]);
        *(us4_t*)(&((unsigned short*)C)[(size_t)col * M + rbase]) = t;
      }
    }
  } else {
#pragma unroll
    for (int i = 0; i < 4; ++i) {
      const int rbase = m0 + wr + i * 16 + quad * 4;
#pragma unroll
      for (int j = 0; j < 4; ++j) {
        const int col = n0 + wc + j * 16 + l16;
#pragma unroll
        for (int rg = 0; rg < 4; ++rg) {
          const size_t idx = (size_t)(rbase + rg) * N + col;
          if (fC) ((float*)C)[idx] = acc[i][j][rg];
          else    ((unsigned short*)C)[idx] = f2b(acc[i][j][rg]);
        }
      }
    }
  }
}

// ---------------------------------------------------------------------------
// RoPE in-place on bf16 X = (B,S,nh,128), vectorized 8 elems/thread.
// out[j] = x[j]*cos[s,64+j] - x[64+j]*sin[s,64+j]; out[64+j] = x2*c + x1*s.
// mode: 0 = device probe (offset 2048, cos|sin), 1 = force fp32, 2 = bf16.
// ---------------------------------------------------------------------------
__global__ __launch_bounds__(256) void rope_kernel(
    unsigned short* __restrict__ X,
    const void* __restrict__ cosb,
    const void* __restrict__ sinb,
    int log2nh, int mode)
{
  bool f;
  if (mode == 1)      f = true;
  else if (mode == 2) f = false;
  else f = probe_is_f32_off(cosb, 2048) | probe_is_f32_off(sinb, 2048);
  const size_t idx = (size_t)blockIdx.x * 256 + threadIdx.x;
  const int jb = (int)(idx & 7) * 8;
  const size_t row = idx >> 3;                 // (b*S+s)*nh + h
  const int s = (int)((row >> log2nh) & 1023);
  unsigned short* p = X + row * 128;
  union { s8_t v; unsigned short u[8]; } ua, ub, o1, o2;
  ua.v = *(const s8_t*)(p + jb);
  ub.v = *(const s8_t*)(p + 64 + jb);
#pragma unroll
  for (int j = 0; j < 8; ++j) {
    const int ci = s * 128 + 64 + jb + j;
    const float c  = f ? ((const float*)cosb)[ci] : b2f(((const unsigned short*)cosb)[ci]);
    const float sn = f ? ((const float*)sinb)[ci] : b2f(((const unsigned short*)sinb)[ci]);
    const float x1 = b2f(ua.u[j]);
    const float x2 = b2f(ub.u[j]);
    o1.u[j] = f2b(x1 * c - x2 * sn);
    o2.u[j] = f2b(x2 * c + x1 * sn);
  }
  *(s8_t*)(p + jb)      = o1.v;
  *(s8_t*)(p + 64 + jb) = o2.v;
}

// ---------------------------------------------------------------------------
// Attention: one block per (b, h, 16 q-rows), S=1024. O aliases Q (in-place).
// XCD-swizzled bid: hardware wg w runs logical block (w&7)*1024 + (w>>3),
// so XCD x owns logical range [x*1024,(x+1)*1024) = 4 complete (b,kh) panel
// groups -> K/V (2MB) L2-resident per XCD, fetched once.
// K direct from global; V direct from global in TRANSPOSED layout
// Vt[kh*128+d][b*1024+s]. Q fragments hoisted to registers for phase 1.
// ---------------------------------------------------------------------------
__global__ __launch_bounds__(256, 4) void attn_kernel(
    unsigned short* O,
    const unsigned short* Q,
    const unsigned short* __restrict__ Kb,
    const unsigned short* __restrict__ Vt)
{
  constexpr int S = 1024, HQ = 32, HKV = 8, HD = 128;
  constexpr int SCP = 1048;
  constexpr int QP  = 152;
  constexpr float SCALE = 0.08838834764831845f;  // 1/sqrt(128)
  __shared__ unsigned short sc[16 * SCP];
  __shared__ unsigned short sq[16 * QP];
  __shared__ float s_linv[16];

  const int bid = (((int)blockIdx.x & 7) << 10) | ((int)blockIdx.x >> 3);
  const int qt = bid & 63;
  const int h  = (bid >> 6) & 31;
  const int b  = bid >> 11;
  const int kh = h >> 2;
  const int tid  = threadIdx.x;
  const int lane = tid & 63;
  const int wv   = tid >> 6;
  const int quad = lane >> 4;
  const int l16  = lane & 15;

  const unsigned short* Qg = Q  + ((size_t)(b * S + qt * 16) * HQ + h) * HD;
  const unsigned short* Kg = Kb + ((size_t)b * S * HKV + kh) * HD;
  const unsigned short* Vg = Vt + ((size_t)kh * HD) * 4096 + (size_t)b * S;

  {
    const int r = tid >> 4, c = (tid & 15) * 8;
    *(s8_t*)(&sq[r * QP + c]) = *(const s8_t*)(Qg + (size_t)r * (HQ * HD) + c);
  }
  __syncthreads();

  // ---- phase 1: scores (K direct from global, Q hoisted to regs) ----
  s8_t qa[4];
#pragma unroll
  for (int kc = 0; kc < 4; ++kc)
    qa[kc] = *(const s8_t*)(&sq[l16 * QP + kc * 32 + quad * 8]);
#pragma unroll 2
  for (int kt = 0; kt < 16; ++kt) {
    const int ks = wv * 256 + kt * 16;
    f4_t acc = (f4_t){0.f, 0.f, 0.f, 0.f};
#pragma unroll
    for (int kc = 0; kc < 4; ++kc) {
      const s8_t kf = *(const s8_t*)(Kg + (size_t)(ks + l16) * (HKV * HD) + kc * 32 + quad * 8);
      acc = MFMA16(qa[kc], kf, acc);
    }
#pragma unroll
    for (int rg = 0; rg < 4; ++rg)
      sc[(quad * 4 + rg) * SCP + ks + l16] = f2b(acc[rg] * SCALE);
  }
  __syncthreads();

  // ---- phase 2: softmax (vectorized b128 row passes) ----
  {
    const int r = tid >> 4, c0 = tid & 15;
    unsigned short* srow = &sc[r * SCP + c0 * 8];
    float mx = -1e30f;
#pragma unroll
    for (int u = 0; u < 8; ++u) {
      union { s8_t v; unsigned short us[8]; } t;
      t.v = *(const s8_t*)(srow + u * 128);
#pragma unroll
      for (int j = 0; j < 8; ++j) mx = fmaxf(mx, b2f(t.us[j]));
    }
#pragma unroll
    for (int off = 8; off; off >>= 1) mx = fmaxf(mx, __shfl_xor(mx, off, 16));
    float sum = 0.f;
#pragma unroll
    for (int u = 0; u < 8; ++u) {
      union { s8_t v; unsigned short us[8]; } t;
      t.v = *(const s8_t*)(srow + u * 128);
#pragma unroll
      for (int j = 0; j < 8; ++j) {
        const float e = __expf(b2f(t.us[j]) - mx);
        sum += e;
        t.us[j] = f2b(e);
      }
      *(s8_t*)(srow + u * 128) = t.v;
    }
#pragma unroll
    for (int off = 8; off; off >>= 1) sum += __shfl_xor(sum, off, 16);
    if (c0 == 0) s_linv[r] = 1.0f / sum;
  }
  __syncthreads();

  // ---- phase 3: O = P @ Vt (V direct from global, no barriers) ----
  f4_t oacc[2];
  oacc[0] = (f4_t){0.f, 0.f, 0.f, 0.f};
  oacc[1] = (f4_t){0.f, 0.f, 0.f, 0.f};
  const unsigned short* vb0 = Vg + (size_t)(wv * 32 + l16) * 4096 + quad * 8;
  const unsigned short* vb1 = vb0 + (size_t)16 * 4096;
  const unsigned short* prow = &sc[l16 * SCP + quad * 8];
#pragma unroll 4
  for (int ck = 0; ck < 16; ++ck) {
#pragma unroll
    for (int kc = 0; kc < 2; ++kc) {
      const int ko = ck * 64 + kc * 32;
      const s8_t pa = *(const s8_t*)(prow + ko);
      const s8_t v0 = *(const s8_t*)(vb0 + ko);
      const s8_t v1 = *(const s8_t*)(vb1 + ko);
      oacc[0] = MFMA16(pa, v0, oacc[0]);
      oacc[1] = MFMA16(pa, v1, oacc[1]);
    }
  }

#pragma unroll
  for (int dt = 0; dt < 2; ++dt)
#pragma unroll
    for (int rg = 0; rg < 4; ++rg) {
      const int r = quad * 4 + rg;
      const int d = wv * 32 + dt * 16 + l16;
      O[((size_t)(b * S + qt * 16 + r) * HQ + h) * HD + d] =
          f2b(oacc[dt][rg] * s_linv[r]);
    }
}

// ---------------------------------------------------------------------------
extern "C" void kernel_launch(void* const* d_in, const int* in_sizes, int n_in,
                              void* d_out, int out_size, void* d_ws, size_t ws_size,
                              hipStream_t stream)
{
  const void* hs   = d_in[0];
  const void* cosb = d_in[1];
  const void* sinb = d_in[2];
  const void* Wq   = d_in[3];
  const void* Wk   = d_in[4];
  const void* Wv   = d_in[5];
  const void* Wo   = d_in[6];

  const size_t MB = (size_t)1 << 20;
  // fp32 input mode <=> hs is (4,1024,4096) fp32 = 64MB (bf16 mode: 32MB).
  const bool f32in = (n_in >= 1 && in_sizes && in_sizes[0] == (int)(64 * MB));
  // cos/sin dtype for rope: decide host-side when sizes match; else probe.
  int rmode = 0;
  if (in_sizes && n_in >= 2) {
    if (in_sizes[1] == 524288) rmode = 1;        // (1,1024,128) fp32
    else if (in_sizes[1] == 262144) rmode = 2;   // (1,1024,128) bf16
  }

  unsigned short* Qb = (unsigned short*)d_ws;                    // ws[0,32M)
  unsigned short* Kb = (unsigned short*)d_out;                   // d_out[0,8M)
  unsigned short* Vt = (unsigned short*)d_out + 4194304;         // d_out[8,16M)

  // One-shot bf16 operand conversion (fp32 mode only; layout gated on sizes).
  const void* hsA = hs;
  if (f32in && out_size >= (int)(48 * MB)) {
    unsigned short* hs_b = (unsigned short*)d_out + 8388608;     // d_out[16,48M)
    cvt_to_bf16<<<8192, 256, 0, stream>>>(hs_b, hs);
    hsA = hs_b;
  }
  const void* WkB = Wk;
  const void* WvB = Wv;
  if (f32in && out_size >= (int)(64 * MB)) {
    unsigned short* wk_b = (unsigned short*)d_out + 25165824;    // d_out[48,56M)
    unsigned short* wv_b = (unsigned short*)d_out + 29360128;    // d_out[56,64M)
    cvt_to_bf16<<<2048, 256, 0, stream>>>(wk_b, Wk);
    cvt_to_bf16<<<2048, 256, 0, stream>>>(wv_b, Wv);
    WkB = wk_b;
    WvB = wv_b;
  }
  const void* WqB = Wq;
  if (f32in && ws_size >= 64 * MB) {
    unsigned short* wq_b = (unsigned short*)d_ws + 16777216;     // ws[32,64M)
    cvt_to_bf16<<<8192, 256, 0, stream>>>(wq_b, Wq);
    WqB = wq_b;
  }
  const void* WoB = Wo;
  if (f32in && ws_size >= 96 * MB) {
    unsigned short* wo_b = (unsigned short*)d_ws + 33554432;     // ws[64,96M)
    cvt_to_bf16<<<8192, 256, 0, stream>>>(wo_b, Wo);
    WoB = wo_b;
  }

  gemm_bt<<<dim3(32,  8), 256, 0, stream>>>(Kb, hsA, WkB, 4096, 1024, 4096,
                                            hsA, WkB, nullptr, 0);
  gemm_bt<<<dim3(32,  8), 256, 0, stream>>>(Vt, hsA, WvB, 4096, 1024, 4096,
                                            hsA, WvB, nullptr, 1);
  gemm_bt<<<dim3(32, 32), 256, 0, stream>>>(Qb, hsA, WqB, 4096, 4096, 4096,
                                            hsA, WqB, nullptr, 0);
  rope_kernel<<<4096, 256, 0, stream>>>(Qb, cosb, sinb, 5, rmode);
  rope_kernel<<<1024, 256, 0, stream>>>(Kb, cosb, sinb, 3, rmode);
  attn_kernel<<<4 * 32 * 64, 256, 0, stream>>>(Qb, Qb, Kb, Vt);
  // final projection: A=Qb (bf16), B=Wo(/bf16 copy), C=d_out (input dtype)
  gemm_bt<<<dim3(32, 32), 256, 0, stream>>>(d_out, Qb, WoB, 4096, 4096, 4096,
                                            nullptr, WoB, hs, 0);
}